// Round 7
// baseline (4968.873 us; speedup 1.0000x reference)
//
#include <hip/hip_runtime.h>
#include <hip/hip_bf16.h>

// ---- problem constants ----
#define BSZ 2
#define LSEQ 1024
#define DMODEL 768
#define NLAYER 4
#define DINNER 1536
#define DSTATE 16
#define DCONV 4
#define DTRANK 48
#define NCHUNK 64
#define CLEN 16
#define XDSTR 128
#define XZLD (2 * DINNER)
#define GRIDN 768

typedef __bf16 bf16x8_t __attribute__((ext_vector_type(8)));
typedef float f32x4_t __attribute__((ext_vector_type(4)));
typedef unsigned short u16x8_t __attribute__((ext_vector_type(8)));
typedef __hip_bfloat16 bf16;

__device__ inline float bfbits2f(unsigned short u) {
    unsigned int x = ((unsigned int)u) << 16;
    return __builtin_bit_cast(float, x);
}
__device__ inline unsigned short f2bfbits(float f) {
    return __builtin_bit_cast(unsigned short, (__bf16)f);
}

// async global->LDS, 16B per lane. dest = wave-uniform base + lane*16 (HW).
__device__ __forceinline__ void gload16(const bf16* g, bf16* l) {
    __builtin_amdgcn_global_load_lds(
        (const __attribute__((address_space(1))) unsigned int*)g,
        (__attribute__((address_space(3))) unsigned int*)l,
        16, 0, 0);
}

__device__ inline float block_reduce_sum(float v, float* sbuf) {
    __syncthreads();
    #pragma unroll
    for (int o = 32; o > 0; o >>= 1) v += __shfl_down(v, o, 64);
    int wid = threadIdx.x >> 6;
    int lane = threadIdx.x & 63;
    if (lane == 0) sbuf[wid] = v;
    __syncthreads();
    if (threadIdx.x == 0) sbuf[0] = (sbuf[0] + sbuf[1]) + (sbuf[2] + sbuf[3]);
    __syncthreads();
    return sbuf[0];
}

// ---- two-level software grid barrier (768 co-resident blocks; monotonic counters) ----
// bar[g*16] : 24 group counters (64B apart); bar[384] root; bar[400] generation
__device__ __forceinline__ void gridbar(unsigned* bar, unsigned bctr, int bid) {
    __syncthreads();
    __threadfence();           // release: flush this block's writes (agent scope, wbL2)
    __syncthreads();           // all waves' fences retired before arrival
    if (threadIdx.x == 0) {
        unsigned* gcnt = bar + (bid >> 5) * 16;   // 24 groups of 32 blocks
        unsigned* rcnt = bar + 384;
        unsigned* gen  = bar + 400;
        if (__hip_atomic_fetch_add(gcnt, 1u, __ATOMIC_RELAXED, __HIP_MEMORY_SCOPE_AGENT)
                == bctr * 32u - 1u) {
            if (__hip_atomic_fetch_add(rcnt, 1u, __ATOMIC_RELAXED, __HIP_MEMORY_SCOPE_AGENT)
                    == bctr * 24u - 1u)
                __hip_atomic_fetch_add(gen, 1u, __ATOMIC_RELAXED, __HIP_MEMORY_SCOPE_AGENT);
        }
        while (__hip_atomic_load(gen, __ATOMIC_RELAXED, __HIP_MEMORY_SCOPE_AGENT) < bctr)
            __builtin_amdgcn_s_sleep(2);
    }
    __syncthreads();
    __threadfence();           // acquire: invalidate stale L1/L2 lines
}

// ---------------- init: weight prep f32->bf16 + embedding + xdbl/bar zero ----------------
#define PN1 (NLAYER * 3072 * 768)
#define PN2 (NLAYER * 768 * 1536)
#define PN3 (NLAYER * 128 * 1536)
#define PN4 (BSZ * LSEQ * DMODEL)
#define PN5 (2 * BSZ * LSEQ * XDSTR)
#define PN6 2048
// total = 17,041,408 -> grid 66568
__global__ __launch_bounds__(256) void init_kernel(
    const int* __restrict__ seq, const float* __restrict__ emb,
    const float* __restrict__ in_w, const float* __restrict__ out_w,
    const float* __restrict__ xp_w,
    float* __restrict__ residual, bf16* __restrict__ in16,
    bf16* __restrict__ out16, bf16* __restrict__ xp16, float* __restrict__ xdbl2,
    unsigned* __restrict__ bar) {
    int idx = blockIdx.x * 256 + threadIdx.x;
    if (idx < PN1) { in16[idx] = __float2bfloat16(in_w[idx]); return; }
    idx -= PN1;
    if (idx < PN2) { out16[idx] = __float2bfloat16(out_w[idx]); return; }
    idx -= PN2;
    if (idx < PN3) {
        int l = idx / (128 * DINNER);
        int r = idx - l * (128 * DINNER);
        int e = r / DINNER;
        int k = r - e * DINNER;
        xp16[idx] = (e < 80) ? __float2bfloat16(xp_w[((size_t)l * 80 + e) * DINNER + k])
                             : __float2bfloat16(0.f);
        return;
    }
    idx -= PN3;
    if (idx < PN4) {
        int bl = idx / DMODEL;
        int dd = idx - bl * DMODEL;
        residual[idx] = emb[(size_t)seq[bl] * DMODEL + dd];
        return;
    }
    idx -= PN4;
    if (idx < PN5) { xdbl2[idx] = 0.f; return; }
    idx -= PN5;
    if (idx < PN6) bar[idx] = 0u;
}

// ================= persistent mega-kernel: whole forward =================
#define UCHUNKS (DINNER / 8)   // 192
__global__ __launch_bounds__(256, 3) void mega_kernel(
    const int* __restrict__ mask,
    const float* __restrict__ norm_w_a, const float* __restrict__ conv_w_a,
    const float* __restrict__ conv_b_a, const float* __restrict__ dt_w_a,
    const float* __restrict__ dt_b_a, const float* __restrict__ A_log_a,
    const float* __restrict__ D_skip_a, const float* __restrict__ normf_w,
    float* __restrict__ residual, bf16* __restrict__ hn16, bf16* __restrict__ xz16,
    float* __restrict__ xdbl, bf16* __restrict__ uy16,
    float* __restrict__ Psum, float* __restrict__ Ssum, float* __restrict__ Dbuf,
    const bf16* __restrict__ in16, const bf16* __restrict__ out16,
    const bf16* __restrict__ xp16,
    unsigned* __restrict__ bar, float* __restrict__ out) {

    __shared__ __align__(16) char ldsb[24640];
    bf16 (*As128)[64] = (bf16(*)[64])ldsb;              // 128x64 (16KB)
    bf16 (*As64)[64]  = (bf16(*)[64])ldsb;              // 64x64 view
    bf16 (*Bs64)[64]  = (bf16(*)[64])(ldsb + 16384);    // 64x64 (8KB)
    float* sbuf       = (float*)(ldsb + 24576);         // 8 floats

    const int bid = blockIdx.x;
    const int tid = threadIdx.x;
    const int wave = tid >> 6;
    const int lane = tid & 63;
    const int quad = lane >> 4;
    const int l16 = lane & 15;
    const int lr = lane >> 3;
    const int lc = (lane & 7) ^ lr;
    const int sx = (l16 & 7) << 3;

    float* P0 = Psum;
    float* P1 = Psum + (size_t)BSZ * LSEQ * DMODEL;
    float* P2 = Ssum;
    float* P3 = Ssum + (size_t)BSZ * LSEQ * DMODEL;

    unsigned bctr = 0;

    for (int il = 0; il < NLAYER; ++il) {
        float* xd_cur = xdbl + (size_t)(il & 1) * (BSZ * LSEQ * XDSTR);
        float* xd_nxt = xdbl + (size_t)((il + 1) & 1) * (BSZ * LSEQ * XDSTR);
        const float* nw = norm_w_a + (size_t)il * DMODEL;
        const float* cw = conv_w_a + (size_t)il * DINNER * DCONV;
        const float* cb = conv_b_a + (size_t)il * DINNER;
        const float* dw = dt_w_a + (size_t)il * DINNER * DTRANK;
        const float* db = dt_b_a + (size_t)il * DINNER;
        const float* al = A_log_a + (size_t)il * DINNER * DSTATE;
        const float* dsk = D_skip_a + (size_t)il * DINNER;
        const bf16* inw = in16 + (size_t)il * 3072 * DMODEL;
        const bf16* outw = out16 + (size_t)il * DMODEL * DINNER;
        const bf16* xpw = xp16 + (size_t)il * 128 * DINNER;

        // ---- phase 1: rmsnorm (+ residual accumulate for il>0) ----
        for (int row = bid; row < BSZ * LSEQ; row += GRIDN) {
            size_t basep = (size_t)row * DMODEL;
            float ss = 0.f;
            if (il == 0) {
                for (int i = tid; i < DMODEL; i += 256) {
                    float v = residual[basep + i];
                    ss += v * v;
                }
            } else {
                for (int i = tid; i < DMODEL; i += 256) {
                    float v = residual[basep + i]
                        + ((P0[basep + i] + P1[basep + i]) + (P2[basep + i] + P3[basep + i]));
                    residual[basep + i] = v;
                    ss += v * v;
                }
            }
            ss = block_reduce_sum(ss, sbuf);
            float scale = rsqrtf(ss / (float)DMODEL + 1e-5f);
            for (int i = tid; i < DMODEL; i += 256)
                hn16[basep + i] = __float2bfloat16(residual[basep + i] * scale * nw[i]);
        }
        gridbar(bar, ++bctr, bid);

        // ---- phase 2: in_proj xz16(2048x3072) = hn16 @ inw^T (16x48 tiles) ----
        {
            int bx = bid & 15, by = bid >> 4;
            int bm = bx * 128, bn = by * 64;
            int wm = wave * 32;
            f32x4_t acc[2][4];
            #pragma unroll
            for (int i = 0; i < 2; ++i)
                #pragma unroll
                for (int j = 0; j < 4; ++j) acc[i][j] = (f32x4_t){0.f, 0.f, 0.f, 0.f};
            for (int k0 = 0; k0 < DMODEL; k0 += 64) {
                #pragma unroll
                for (int i = 0; i < 6; ++i) {
                    int ch = wave * 6 + i;
                    if (ch < 16) {
                        int r = ch * 8 + lr;
                        gload16(hn16 + (size_t)(bm + r) * DMODEL + k0 + lc * 8, &As128[ch * 8][0]);
                    } else {
                        int c2 = ch - 16;
                        int r = c2 * 8 + lr;
                        gload16(inw + (size_t)(bn + r) * DMODEL + k0 + lc * 8, &Bs64[c2 * 8][0]);
                    }
                }
                __syncthreads();
                #pragma unroll
                for (int kk = 0; kk < 64; kk += 32) {
                    bf16x8_t af[2], bf[4];
                    #pragma unroll
                    for (int i = 0; i < 2; ++i)
                        af[i] = *(const bf16x8_t*)(&As128[wm + i * 16 + l16][(kk + quad * 8) ^ sx]);
                    #pragma unroll
                    for (int j = 0; j < 4; ++j)
                        bf[j] = *(const bf16x8_t*)(&Bs64[j * 16 + l16][(kk + quad * 8) ^ sx]);
                    #pragma unroll
                    for (int i = 0; i < 2; ++i)
                        #pragma unroll
                        for (int j = 0; j < 4; ++j)
                            acc[i][j] = __builtin_amdgcn_mfma_f32_16x16x32_bf16(af[i], bf[j], acc[i][j], 0, 0, 0);
                }
                __syncthreads();
            }
            int mbase = bm + wm + quad * 4;
            #pragma unroll
            for (int i = 0; i < 2; ++i)
                #pragma unroll
                for (int j = 0; j < 4; ++j) {
                    int n = bn + j * 16 + l16;
                    #pragma unroll
                    for (int r = 0; r < 4; ++r)
                        xz16[(size_t)(mbase + i * 16 + r) * XZLD + n] = __float2bfloat16(acc[i][j][r]);
                }
        }
        gridbar(bar, ++bctr, bid);

        // ---- phase 3: u = silu(conv4(x)+cb) (grid-stride x2) ----
        for (int idx = bid * 256 + tid; idx < BSZ * LSEQ * UCHUNKS; idx += GRIDN * 256) {
            int row = idx / UCHUNKS;
            int d0 = (idx - row * UCHUNKS) * 8;
            int l = row & (LSEQ - 1);
            const u16x8_t Z8 = (u16x8_t){0, 0, 0, 0, 0, 0, 0, 0};
            u16x8_t xa[4];
            #pragma unroll
            for (int t = 0; t < 4; ++t)
                xa[t] = (l >= 3 - t) ? *(const u16x8_t*)(xz16 + (size_t)(row - 3 + t) * XZLD + d0) : Z8;
            u16x8_t r;
            #pragma unroll
            for (int j = 0; j < 8; ++j) {
                float4 cwv = *(const float4*)(cw + (size_t)(d0 + j) * 4);
                float a = cb[d0 + j]
                    + bfbits2f(xa[0][j]) * cwv.x + bfbits2f(xa[1][j]) * cwv.y
                    + bfbits2f(xa[2][j]) * cwv.z + bfbits2f(xa[3][j]) * cwv.w;
                a = a / (1.f + __expf(-a));
                r[j] = f2bfbits(a);
            }
            *(u16x8_t*)(uy16 + (size_t)row * DINNER + d0) = r;
        }
        gridbar(bar, ++bctr, bid);

        // ---- phase 4: x_proj xdbl = u @ xpw^T, split-K=8 atomics (512 blocks) ----
        if (bid < 512) {
            int bx = bid & 31, by = (bid >> 5) & 1, bz = bid >> 6;
            int bm = bx * 64, bn = by * 64;
            int kbeg = bz * 192, kend = kbeg + 192;
            f32x4_t acc[4];
            #pragma unroll
            for (int i = 0; i < 4; ++i) acc[i] = (f32x4_t){0.f, 0.f, 0.f, 0.f};
            for (int k0 = kbeg; k0 < kend; k0 += 64) {
                #pragma unroll
                for (int i = 0; i < 4; ++i) {
                    int ch = wave * 4 + i;
                    if (ch < 8) {
                        int r = ch * 8 + lr;
                        gload16(uy16 + (size_t)(bm + r) * DINNER + k0 + lc * 8, &As64[ch * 8][0]);
                    } else {
                        int c2 = ch - 8;
                        int r = c2 * 8 + lr;
                        gload16(xpw + (size_t)(bn + r) * DINNER + k0 + lc * 8, &Bs64[c2 * 8][0]);
                    }
                }
                __syncthreads();
                #pragma unroll
                for (int kk = 0; kk < 64; kk += 32) {
                    bf16x8_t af = *(const bf16x8_t*)(&As64[wave * 16 + l16][(kk + quad * 8) ^ sx]);
                    #pragma unroll
                    for (int i = 0; i < 4; ++i) {
                        bf16x8_t bv = *(const bf16x8_t*)(&Bs64[i * 16 + l16][(kk + quad * 8) ^ sx]);
                        acc[i] = __builtin_amdgcn_mfma_f32_16x16x32_bf16(af, bv, acc[i], 0, 0, 0);
                    }
                }
                __syncthreads();
            }
            int m0 = bm + wave * 16 + quad * 4;
            #pragma unroll
            for (int i = 0; i < 4; ++i) {
                int n = bn + i * 16 + l16;
                #pragma unroll
                for (int r = 0; r < 4; ++r)
                    atomicAdd(&xd_cur[(size_t)(m0 + r) * XDSTR + n], acc[i][r]);
            }
        }
        gridbar(bar, ++bctr, bid);

        // ---- phase 5: scanA (chunk P,S; store delta; zero next xdbl) ----
        {
            int gtid = bid * 256 + tid;
            int d = gtid % DINNER;
            int c = (gtid / DINNER) % NCHUNK;
            int b = gtid / (DINNER * NCHUNK);
            float dtw[DTRANK];
            #pragma unroll
            for (int j = 0; j < DTRANK; j += 4)
                *(float4*)(dtw + j) = *(const float4*)(dw + (size_t)d * DTRANK + j);
            float dtbd = db[d];
            float Av[DSTATE], P[DSTATE], S[DSTATE];
            #pragma unroll
            for (int s = 0; s < DSTATE; ++s) {
                Av[s] = -__expf(al[d * DSTATE + s]);
                P[s] = 1.f; S[s] = 0.f;
            }
            int t0 = c * CLEN;
            int rowb = b * LSEQ;
            for (int i = 0; i < CLEN; ++i) {
                int row = rowb + t0 + i;
                const float* xrow = xd_cur + (size_t)row * XDSTR;
                float acc = dtbd;
                #pragma unroll
                for (int j = 0; j < DTRANK; j += 4) {
                    float4 xv = *(const float4*)(xrow + j);
                    acc += xv.x * dtw[j] + xv.y * dtw[j + 1] + xv.z * dtw[j + 2] + xv.w * dtw[j + 3];
                }
                float dl = (acc > 20.f) ? acc : log1pf(__expf(acc));
                Dbuf[(size_t)row * DINNER + d] = dl;
                float u = __bfloat162float(uy16[(size_t)row * DINNER + d]);
                float bt = dl * u;
                const float4* Bp = (const float4*)(xrow + DTRANK);
                float4 B0 = Bp[0], B1 = Bp[1], B2 = Bp[2], B3 = Bp[3];
                float Bv[DSTATE] = {B0.x,B0.y,B0.z,B0.w, B1.x,B1.y,B1.z,B1.w,
                                    B2.x,B2.y,B2.z,B2.w, B3.x,B3.y,B3.z,B3.w};
                #pragma unroll
                for (int s = 0; s < DSTATE; ++s) {
                    float a = __expf(dl * Av[s]);
                    P[s] *= a;
                    S[s] = a * S[s] + bt * Bv[s];
                }
            }
            size_t basea = ((size_t)(b * NCHUNK + c) * DSTATE) * DINNER + d;
            #pragma unroll
            for (int s = 0; s < DSTATE; ++s) {
                Psum[basea + (size_t)s * DINNER] = P[s];
                Ssum[basea + (size_t)s * DINNER] = S[s];
            }
            for (int z = gtid; z < BSZ * LSEQ * XDSTR; z += BSZ * NCHUNK * DINNER)
                xd_nxt[z] = 0.f;
        }
        gridbar(bar, ++bctr, bid);

        // ---- phase 6: scanB in-place exclusive prefix (192 blocks) ----
        if (bid < 192) {
            int gtid = bid * 256 + tid;
            int d = gtid % DINNER;
            int s = (gtid / DINNER) % DSTATE;
            int b = gtid / (DINNER * DSTATE);
            float h = 0.f;
            for (int c = 0; c < NCHUNK; ++c) {
                size_t idx = ((size_t)(b * NCHUNK + c) * DSTATE + s) * DINNER + d;
                float p = Psum[idx];
                Psum[idx] = h;
                h = p * h + Ssum[idx];
            }
        }
        gridbar(bar, ++bctr, bid);

        // ---- phase 7: scanC (y = (scan + u*D)*silu(z), in-place into uy16) ----
        {
            int gtid = bid * 256 + tid;
            int d = gtid % DINNER;
            int c = (gtid / DINNER) % NCHUNK;
            int b = gtid / (DINNER * NCHUNK);
            float Av[DSTATE], h[DSTATE];
            size_t basea = ((size_t)(b * NCHUNK + c) * DSTATE) * DINNER + d;
            #pragma unroll
            for (int s = 0; s < DSTATE; ++s) {
                Av[s] = -__expf(al[d * DSTATE + s]);
                h[s] = Psum[basea + (size_t)s * DINNER];
            }
            float Dsk = dsk[d];
            int t0 = c * CLEN;
            int rowb = b * LSEQ;
            for (int i = 0; i < CLEN; ++i) {
                int row = rowb + t0 + i;
                const float* xrow = xd_cur + (size_t)row * XDSTR;
                float dl = Dbuf[(size_t)row * DINNER + d];
                float u = __bfloat162float(uy16[(size_t)row * DINNER + d]);
                float bt = dl * u;
                const float4* Bp = (const float4*)(xrow + DTRANK);
                float4 B0 = Bp[0], B1 = Bp[1], B2 = Bp[2], B3 = Bp[3];
                const float4* Cp = (const float4*)(xrow + DTRANK + DSTATE);
                float4 C0 = Cp[0], C1 = Cp[1], C2 = Cp[2], C3 = Cp[3];
                float Bv[DSTATE] = {B0.x,B0.y,B0.z,B0.w, B1.x,B1.y,B1.z,B1.w,
                                    B2.x,B2.y,B2.z,B2.w, B3.x,B3.y,B3.z,B3.w};
                float Cv[DSTATE] = {C0.x,C0.y,C0.z,C0.w, C1.x,C1.y,C1.z,C1.w,
                                    C2.x,C2.y,C2.z,C2.w, C3.x,C3.y,C3.z,C3.w};
                float acc = 0.f;
                #pragma unroll
                for (int s = 0; s < DSTATE; ++s) {
                    float a = __expf(dl * Av[s]);
                    h[s] = a * h[s] + bt * Bv[s];
                    acc += h[s] * Cv[s];
                }
                float zv = __bfloat162float(xz16[(size_t)row * XZLD + DINNER + d]);
                float sz = zv / (1.f + __expf(-zv));
                uy16[(size_t)row * DINNER + d] = __float2bfloat16((acc + u * Dsk) * sz);
            }
        }
        gridbar(bar, ++bctr, bid);

        // ---- phase 8: out_proj partials P0..P3 = y @ outw^T (16x12x4 tiles) ----
        {
            int bx = bid & 15, by = (bid >> 4) % 12, bz = bid / 192;
            int bm = bx * 128, bn = by * 64;
            int kbeg = bz * (DINNER / 4), kend = kbeg + (DINNER / 4);
            int wm = wave * 32;
            float* Cf = (bz == 0) ? P0 : (bz == 1) ? P1 : (bz == 2) ? P2 : P3;
            f32x4_t acc[2][4];
            #pragma unroll
            for (int i = 0; i < 2; ++i)
                #pragma unroll
                for (int j = 0; j < 4; ++j) acc[i][j] = (f32x4_t){0.f, 0.f, 0.f, 0.f};
            for (int k0 = kbeg; k0 < kend; k0 += 64) {
                #pragma unroll
                for (int i = 0; i < 6; ++i) {
                    int ch = wave * 6 + i;
                    if (ch < 16) {
                        int r = ch * 8 + lr;
                        gload16(uy16 + (size_t)(bm + r) * DINNER + k0 + lc * 8, &As128[ch * 8][0]);
                    } else {
                        int c2 = ch - 16;
                        int r = c2 * 8 + lr;
                        gload16(outw + (size_t)(bn + r) * DINNER + k0 + lc * 8, &Bs64[c2 * 8][0]);
                    }
                }
                __syncthreads();
                #pragma unroll
                for (int kk = 0; kk < 64; kk += 32) {
                    bf16x8_t af[2], bf[4];
                    #pragma unroll
                    for (int i = 0; i < 2; ++i)
                        af[i] = *(const bf16x8_t*)(&As128[wm + i * 16 + l16][(kk + quad * 8) ^ sx]);
                    #pragma unroll
                    for (int j = 0; j < 4; ++j)
                        bf[j] = *(const bf16x8_t*)(&Bs64[j * 16 + l16][(kk + quad * 8) ^ sx]);
                    #pragma unroll
                    for (int i = 0; i < 2; ++i)
                        #pragma unroll
                        for (int j = 0; j < 4; ++j)
                            acc[i][j] = __builtin_amdgcn_mfma_f32_16x16x32_bf16(af[i], bf[j], acc[i][j], 0, 0, 0);
                }
                __syncthreads();
            }
            int mbase = bm + wm + quad * 4;
            #pragma unroll
            for (int i = 0; i < 2; ++i)
                #pragma unroll
                for (int j = 0; j < 4; ++j) {
                    int n = bn + j * 16 + l16;
                    #pragma unroll
                    for (int r = 0; r < 4; ++r)
                        Cf[(size_t)(mbase + i * 16 + r) * DMODEL + n] = acc[i][j][r];
                }
        }
        gridbar(bar, ++bctr, bid);
    }

    // ---- final: last-token rmsnorm over res + P0..P3 (blocks 0,1) ----
    if (bid < BSZ) {
        int b = bid;
        float cnt = 0.f;
        for (int i = tid; i < LSEQ; i += 256) cnt += (float)mask[b * LSEQ + i];
        cnt = block_reduce_sum(cnt, sbuf);
        int last = (int)cnt - 1;
        size_t basep = ((size_t)b * LSEQ + last) * DMODEL;
        float ss = 0.f;
        for (int i = tid; i < DMODEL; i += 256) {
            float v = residual[basep + i]
                + ((P0[basep + i] + P1[basep + i]) + (P2[basep + i] + P3[basep + i]));
            ss += v * v;
        }
        ss = block_reduce_sum(ss, sbuf);
        float scale = rsqrtf(ss / (float)DMODEL + 1e-5f);
        for (int i = tid; i < DMODEL; i += 256) {
            float v = residual[basep + i]
                + ((P0[basep + i] + P1[basep + i]) + (P2[basep + i] + P3[basep + i]));
            out[b * DMODEL + i] = v * scale * normf_w[i];
        }
    }
}

extern "C" void kernel_launch(void* const* d_in, const int* in_sizes, int n_in,
                              void* d_out, int out_size, void* d_ws, size_t ws_size,
                              hipStream_t stream) {
    const int*   seq      = (const int*)d_in[0];
    const int*   mask     = (const int*)d_in[1];
    const float* emb      = (const float*)d_in[2];
    const float* norm_w   = (const float*)d_in[3];
    const float* in_w     = (const float*)d_in[4];
    const float* conv_w   = (const float*)d_in[5];
    const float* conv_b   = (const float*)d_in[6];
    const float* xp_w     = (const float*)d_in[7];
    const float* dt_w     = (const float*)d_in[8];
    const float* dt_b     = (const float*)d_in[9];
    const float* A_log    = (const float*)d_in[10];
    const float* D_skip   = (const float*)d_in[11];
    const float* out_w    = (const float*)d_in[12];
    const float* normf_w  = (const float*)d_in[13];
    float* out = (float*)d_out;

    char* ws = (char*)d_ws;
    float* residual = (float*)(ws);                      //  6,291,456
    bf16*  hn16     = (bf16*)(ws + 6291456);             //  3,145,728
    bf16*  xz16     = (bf16*)(ws + 9437184);             // 12,582,912
    float* xdbl     = (float*)(ws + 22020096);           //  2,097,152 (2 buffers)
    bf16*  uy16     = (bf16*)(ws + 24117248);            //  6,291,456 (u, then y)
    float* Psum     = (float*)(ws + 30408704);           // 12,582,912 (P->h0->P0/P1)
    float* Ssum     = (float*)(ws + 42991616);           // 12,582,912 (S->P2/P3)
    float* Dbuf     = (float*)(ws + 55574528);           // 12,582,912 (delta)
    bf16*  in16     = (bf16*)(ws + 68157440);            // 18,874,368
    bf16*  out16    = (bf16*)(ws + 87031808);            //  9,437,184
    bf16*  xp16     = (bf16*)(ws + 96468992);            //  1,572,864
    unsigned* bar   = (unsigned*)(ws + 98041856);        //  8,192 (barrier words)
                                                         // total 98,050,048 bytes

    init_kernel<<<66568, 256, 0, stream>>>(seq, emb, in_w, out_w, xp_w,
                                           residual, in16, out16, xp16, xdbl, bar);

    mega_kernel<<<GRIDN, 256, 0, stream>>>(
        mask, norm_w, conv_w, conv_b, dt_w, dt_b, A_log, D_skip, normf_w,
        residual, hn16, xz16, xdbl, uy16, Psum, Ssum, Dbuf,
        in16, out16, xp16, bar, out);
}

// Round 8
// 686.960 us; speedup vs baseline: 7.2331x; 7.2331x over previous
//
#include <hip/hip_runtime.h>
#include <hip/hip_bf16.h>

// ---- problem constants ----
#define BSZ 2
#define LSEQ 1024
#define DMODEL 768
#define NLAYER 4
#define DINNER 1536
#define DSTATE 16
#define DCONV 4
#define DTRANK 48
#define NCHUNK 64
#define CLEN 16
#define XDSTR 128
#define XZLD (2 * DINNER)

typedef __bf16 bf16x8_t __attribute__((ext_vector_type(8)));
typedef float f32x4_t __attribute__((ext_vector_type(4)));
typedef unsigned short u16x8_t __attribute__((ext_vector_type(8)));
typedef __hip_bfloat16 bf16;

__device__ inline float bfbits2f(unsigned short u) {
    unsigned int x = ((unsigned int)u) << 16;
    return __builtin_bit_cast(float, x);
}
__device__ inline unsigned short f2bfbits(float f) {
    return __builtin_bit_cast(unsigned short, (__bf16)f);
}

// async global->LDS, 16B per lane. dest = wave-uniform base + lane*16 (HW).
__device__ __forceinline__ void gload16(const bf16* g, bf16* l) {
    __builtin_amdgcn_global_load_lds(
        (const __attribute__((address_space(1))) unsigned int*)g,
        (__attribute__((address_space(3))) unsigned int*)l,
        16, 0, 0);
}

__device__ inline float block_reduce_sum(float v, float* sbuf) {
    __syncthreads();
    #pragma unroll
    for (int o = 32; o > 0; o >>= 1) v += __shfl_down(v, o, 64);
    int wid = threadIdx.x >> 6;
    int lane = threadIdx.x & 63;
    if (lane == 0) sbuf[wid] = v;
    __syncthreads();
    if (threadIdx.x == 0) sbuf[0] = (sbuf[0] + sbuf[1]) + (sbuf[2] + sbuf[3]);
    __syncthreads();
    return sbuf[0];
}

// ---------------- init: weight prep f32->bf16 + embedding + xdbl zero ----------------
#define PN1 (NLAYER * 3072 * 768)
#define PN2 (NLAYER * 768 * 1536)
#define PN3 (NLAYER * 128 * 1536)
#define PN4 (BSZ * LSEQ * DMODEL)
#define PN5 (2 * BSZ * LSEQ * XDSTR)
// total = 17,039,360 -> grid 66560
__global__ __launch_bounds__(256) void init_kernel(
    const int* __restrict__ seq, const float* __restrict__ emb,
    const float* __restrict__ in_w, const float* __restrict__ out_w,
    const float* __restrict__ xp_w,
    float* __restrict__ residual, bf16* __restrict__ in16,
    bf16* __restrict__ out16, bf16* __restrict__ xp16, float* __restrict__ xdbl2) {
    int idx = blockIdx.x * 256 + threadIdx.x;
    if (idx < PN1) { in16[idx] = __float2bfloat16(in_w[idx]); return; }
    idx -= PN1;
    if (idx < PN2) { out16[idx] = __float2bfloat16(out_w[idx]); return; }
    idx -= PN2;
    if (idx < PN3) {
        int l = idx / (128 * DINNER);
        int r = idx - l * (128 * DINNER);
        int e = r / DINNER;
        int k = r - e * DINNER;
        xp16[idx] = (e < 80) ? __float2bfloat16(xp_w[((size_t)l * 80 + e) * DINNER + k])
                             : __float2bfloat16(0.f);
        return;
    }
    idx -= PN3;
    if (idx < PN4) {
        int bl = idx / DMODEL;
        int dd = idx - bl * DMODEL;
        residual[idx] = emb[(size_t)seq[bl] * DMODEL + dd];
        return;
    }
    idx -= PN4;
    xdbl2[idx] = 0.f;
}

// ---------------- rmsnorm (layer 0) -> bf16 ----------------
__global__ __launch_bounds__(256) void rmsnorm_kernel(
    const float* __restrict__ res, const float* __restrict__ w, bf16* __restrict__ out) {
    __shared__ float sbuf[8];
    int row = blockIdx.x;
    const float* x = res + (size_t)row * DMODEL;
    float ss = 0.f;
    for (int i = threadIdx.x; i < DMODEL; i += 256) { float v = x[i]; ss += v * v; }
    ss = block_reduce_sum(ss, sbuf);
    float scale = rsqrtf(ss / (float)DMODEL + 1e-5f);
    for (int i = threadIdx.x; i < DMODEL; i += 256)
        out[(size_t)row * DMODEL + i] = __float2bfloat16(x[i] * scale * w[i]);
}

// ---------------- rmsnorm with residual += P0..P3 write-back (layers 1..3) ----------------
__global__ __launch_bounds__(256) void rmsnorm_acc_kernel(
    float* __restrict__ res, const float* __restrict__ p0, const float* __restrict__ p1,
    const float* __restrict__ p2, const float* __restrict__ p3,
    const float* __restrict__ w, bf16* __restrict__ out) {
    __shared__ float sbuf[8];
    int row = blockIdx.x;
    size_t base = (size_t)row * DMODEL;
    float ss = 0.f;
    for (int i = threadIdx.x; i < DMODEL; i += 256) {
        float v = res[base + i] + ((p0[base + i] + p1[base + i]) + (p2[base + i] + p3[base + i]));
        res[base + i] = v;
        ss += v * v;
    }
    ss = block_reduce_sum(ss, sbuf);
    float scale = rsqrtf(ss / (float)DMODEL + 1e-5f);
    for (int i = threadIdx.x; i < DMODEL; i += 256)
        out[base + i] = __float2bfloat16(res[base + i] * scale * w[i]);
}

// ---------------- GEMM 128x64 tile, double-buffered gload_lds + XOR swizzle (in_proj) ----------------
__global__ __launch_bounds__(256) void gemm_128x64_g(
    const bf16* __restrict__ A, int lda, const bf16* __restrict__ Bw, int ldb,
    bf16* __restrict__ C16, int ldc, int K) {
    __shared__ bf16 As[2][128][64];
    __shared__ bf16 Bs[2][64][64];
    int tid = threadIdx.x;
    int wave = tid >> 6;
    int lane = tid & 63;
    int quad = lane >> 4;
    int l16 = lane & 15;
    int bm = blockIdx.x * 128;
    int bn = blockIdx.y * 64;
    int wm = wave * 32;
    int lr = lane >> 3;
    int lc = (lane & 7) ^ lr;
    int sx = (l16 & 7) << 3;

    f32x4_t acc[2][4];
    #pragma unroll
    for (int i = 0; i < 2; ++i)
        #pragma unroll
        for (int j = 0; j < 4; ++j) acc[i][j] = (f32x4_t){0.f, 0.f, 0.f, 0.f};

    auto stage = [&](int k0, int pb) {
        #pragma unroll
        for (int i = 0; i < 6; ++i) {
            int ch = wave * 6 + i;
            if (ch < 16) {
                int r = ch * 8 + lr;
                gload16(A + (size_t)(bm + r) * lda + k0 + lc * 8, &As[pb][ch * 8][0]);
            } else {
                int c2 = ch - 16;
                int r = c2 * 8 + lr;
                gload16(Bw + (size_t)(bn + r) * ldb + k0 + lc * 8, &Bs[pb][c2 * 8][0]);
            }
        }
    };
    auto compute = [&](int pb) {
        #pragma unroll
        for (int kk = 0; kk < 64; kk += 32) {
            bf16x8_t af[2], bf[4];
            #pragma unroll
            for (int i = 0; i < 2; ++i)
                af[i] = *(const bf16x8_t*)(&As[pb][wm + i * 16 + l16][(kk + quad * 8) ^ sx]);
            #pragma unroll
            for (int j = 0; j < 4; ++j)
                bf[j] = *(const bf16x8_t*)(&Bs[pb][j * 16 + l16][(kk + quad * 8) ^ sx]);
            #pragma unroll
            for (int i = 0; i < 2; ++i)
                #pragma unroll
                for (int j = 0; j < 4; ++j)
                    acc[i][j] = __builtin_amdgcn_mfma_f32_16x16x32_bf16(af[i], bf[j], acc[i][j], 0, 0, 0);
        }
    };

    stage(0, 0);
    __syncthreads();
    int cur = 0;
    for (int k0 = 64; k0 < K; k0 += 64) {
        stage(k0, cur ^ 1);     // issue next-tile loads (in flight during compute)
        compute(cur);
        __syncthreads();        // drains vmcnt(0): next buffer ready; orders reuse
        cur ^= 1;
    }
    compute(cur);

    int mbase = bm + wm + quad * 4;
    #pragma unroll
    for (int i = 0; i < 2; ++i)
        #pragma unroll
        for (int j = 0; j < 4; ++j) {
            int n = bn + j * 16 + l16;
            #pragma unroll
            for (int r = 0; r < 4; ++r)
                C16[(size_t)(mbase + i * 16 + r) * ldc + n] = __float2bfloat16(acc[i][j][r]);
        }
}

// ---------------- GEMM 64x64 tile, double-buffered, split-K atomicAdd f32 (x_proj) ----------------
__global__ __launch_bounds__(256) void gemm_64_atomic_g(
    const bf16* __restrict__ A, int lda, const bf16* __restrict__ Bw, int ldb,
    float* __restrict__ Cf, int ldc, int K) {
    __shared__ bf16 As[2][64][64];
    __shared__ bf16 Bs[2][64][64];
    int tid = threadIdx.x;
    int wave = tid >> 6;
    int lane = tid & 63;
    int quad = lane >> 4;
    int l16 = lane & 15;
    int bm = blockIdx.x * 64;
    int bn = blockIdx.y * 64;
    int lr = lane >> 3;
    int lc = (lane & 7) ^ lr;
    int sx = (l16 & 7) << 3;
    int kpb = K / gridDim.z;
    int kbeg = blockIdx.z * kpb;
    int kend = kbeg + kpb;

    f32x4_t acc[4];
    #pragma unroll
    for (int i = 0; i < 4; ++i) acc[i] = (f32x4_t){0.f, 0.f, 0.f, 0.f};

    auto stage = [&](int k0, int pb) {
        #pragma unroll
        for (int i = 0; i < 4; ++i) {
            int ch = wave * 4 + i;
            if (ch < 8) {
                int r = ch * 8 + lr;
                gload16(A + (size_t)(bm + r) * lda + k0 + lc * 8, &As[pb][ch * 8][0]);
            } else {
                int c2 = ch - 8;
                int r = c2 * 8 + lr;
                gload16(Bw + (size_t)(bn + r) * ldb + k0 + lc * 8, &Bs[pb][c2 * 8][0]);
            }
        }
    };
    auto compute = [&](int pb) {
        #pragma unroll
        for (int kk = 0; kk < 64; kk += 32) {
            bf16x8_t af = *(const bf16x8_t*)(&As[pb][wave * 16 + l16][(kk + quad * 8) ^ sx]);
            #pragma unroll
            for (int i = 0; i < 4; ++i) {
                bf16x8_t bv = *(const bf16x8_t*)(&Bs[pb][i * 16 + l16][(kk + quad * 8) ^ sx]);
                acc[i] = __builtin_amdgcn_mfma_f32_16x16x32_bf16(af, bv, acc[i], 0, 0, 0);
            }
        }
    };

    stage(kbeg, 0);
    __syncthreads();
    int cur = 0;
    for (int k0 = kbeg + 64; k0 < kend; k0 += 64) {
        stage(k0, cur ^ 1);
        compute(cur);
        __syncthreads();
        cur ^= 1;
    }
    compute(cur);

    int m0 = bm + wave * 16 + quad * 4;
    #pragma unroll
    for (int i = 0; i < 4; ++i) {
        int n = bn + i * 16 + l16;
        #pragma unroll
        for (int r = 0; r < 4; ++r)
            atomicAdd(&Cf[(size_t)(m0 + r) * ldc + n], acc[i][r]);
    }
}

// ---------------- GEMM 128x64 tile, double-buffered, split-K=4 partial stores (out_proj) ----------------
__global__ __launch_bounds__(256) void gemm_128x64_part_g(
    const bf16* __restrict__ A, int lda, const bf16* __restrict__ Bw, int ldb,
    float* __restrict__ P0, float* __restrict__ P1,
    float* __restrict__ P2, float* __restrict__ P3, int ldc, int K) {
    __shared__ bf16 As[2][128][64];
    __shared__ bf16 Bs[2][64][64];
    int tid = threadIdx.x;
    int wave = tid >> 6;
    int lane = tid & 63;
    int quad = lane >> 4;
    int l16 = lane & 15;
    int bm = blockIdx.x * 128;
    int bn = blockIdx.y * 64;
    int wm = wave * 32;
    int lr = lane >> 3;
    int lc = (lane & 7) ^ lr;
    int sx = (l16 & 7) << 3;
    int kpb = K / 4;                      // gridDim.z == 4
    int kbeg = blockIdx.z * kpb;
    int kend = kbeg + kpb;
    float* Cf = (blockIdx.z == 0) ? P0 : (blockIdx.z == 1) ? P1 : (blockIdx.z == 2) ? P2 : P3;

    f32x4_t acc[2][4];
    #pragma unroll
    for (int i = 0; i < 2; ++i)
        #pragma unroll
        for (int j = 0; j < 4; ++j) acc[i][j] = (f32x4_t){0.f, 0.f, 0.f, 0.f};

    auto stage = [&](int k0, int pb) {
        #pragma unroll
        for (int i = 0; i < 6; ++i) {
            int ch = wave * 6 + i;
            if (ch < 16) {
                int r = ch * 8 + lr;
                gload16(A + (size_t)(bm + r) * lda + k0 + lc * 8, &As[pb][ch * 8][0]);
            } else {
                int c2 = ch - 16;
                int r = c2 * 8 + lr;
                gload16(Bw + (size_t)(bn + r) * ldb + k0 + lc * 8, &Bs[pb][c2 * 8][0]);
            }
        }
    };
    auto compute = [&](int pb) {
        #pragma unroll
        for (int kk = 0; kk < 64; kk += 32) {
            bf16x8_t af[2], bf[4];
            #pragma unroll
            for (int i = 0; i < 2; ++i)
                af[i] = *(const bf16x8_t*)(&As[pb][wm + i * 16 + l16][(kk + quad * 8) ^ sx]);
            #pragma unroll
            for (int j = 0; j < 4; ++j)
                bf[j] = *(const bf16x8_t*)(&Bs[pb][j * 16 + l16][(kk + quad * 8) ^ sx]);
            #pragma unroll
            for (int i = 0; i < 2; ++i)
                #pragma unroll
                for (int j = 0; j < 4; ++j)
                    acc[i][j] = __builtin_amdgcn_mfma_f32_16x16x32_bf16(af[i], bf[j], acc[i][j], 0, 0, 0);
        }
    };

    stage(kbeg, 0);
    __syncthreads();
    int cur = 0;
    for (int k0 = kbeg + 64; k0 < kend; k0 += 64) {
        stage(k0, cur ^ 1);
        compute(cur);
        __syncthreads();
        cur ^= 1;
    }
    compute(cur);

    int mbase = bm + wm + quad * 4;
    #pragma unroll
    for (int i = 0; i < 2; ++i)
        #pragma unroll
        for (int j = 0; j < 4; ++j) {
            int n = bn + j * 16 + l16;
            #pragma unroll
            for (int r = 0; r < 4; ++r)
                Cf[(size_t)(mbase + i * 16 + r) * ldc + n] = acc[i][j][r];
        }
}

// ---------------- u = silu(conv4(x)+cb), vectorized x8 (throughput kernel) ----------------
#define UCHUNKS (DINNER / 8)   // 192
__global__ __launch_bounds__(256) void usilu_kernel(
    const bf16* __restrict__ xz16, const float* __restrict__ cw, const float* __restrict__ cb,
    bf16* __restrict__ u16) {
    int idx = blockIdx.x * 256 + threadIdx.x;          // < 2048*192
    int row = idx / UCHUNKS;
    int d0 = (idx - row * UCHUNKS) * 8;
    int l = row & (LSEQ - 1);
    const u16x8_t Z8 = (u16x8_t){0, 0, 0, 0, 0, 0, 0, 0};
    u16x8_t xa[4];
    #pragma unroll
    for (int t = 0; t < 4; ++t)
        xa[t] = (l >= 3 - t) ? *(const u16x8_t*)(xz16 + (size_t)(row - 3 + t) * XZLD + d0) : Z8;
    u16x8_t r;
    #pragma unroll
    for (int j = 0; j < 8; ++j) {
        float4 cwv = *(const float4*)(cw + (size_t)(d0 + j) * 4);
        float a = cb[d0 + j]
            + bfbits2f(xa[0][j]) * cwv.x + bfbits2f(xa[1][j]) * cwv.y
            + bfbits2f(xa[2][j]) * cwv.z + bfbits2f(xa[3][j]) * cwv.w;
        a = a / (1.f + __expf(-a));
        r[j] = f2bfbits(a);
    }
    *(u16x8_t*)(u16 + (size_t)row * DINNER + d0) = r;
}

// ---------------- delta from f32 xdbl row (wave-uniform) + per-thread dtw ----------------
__device__ inline float compute_delta(const float* __restrict__ xrow,
                                      const float* __restrict__ dtw, float dtbd) {
    float acc = dtbd;
    #pragma unroll
    for (int j = 0; j < DTRANK; j += 4) {
        float4 xv = *(const float4*)(xrow + j);
        acc += xv.x * dtw[j] + xv.y * dtw[j + 1] + xv.z * dtw[j + 2] + xv.w * dtw[j + 3];
    }
    return (acc > 20.f) ? acc : log1pf(__expf(acc));
}

// ================= chunked scan (u precomputed; delta stored for phase C) =================
__global__ __launch_bounds__(256) void scan_phaseA(
    const bf16* __restrict__ u16, const float* __restrict__ xdbl,
    const float* __restrict__ dt_w, const float* __restrict__ dt_b,
    const float* __restrict__ A_log,
    float* __restrict__ Psum, float* __restrict__ Ssum,
    float* __restrict__ Dbuf,          // per-(row,d) delta, reused Hin space
    float* __restrict__ xd_next) {
    int gtid = blockIdx.x * 256 + threadIdx.x;
    int d = gtid % DINNER;
    int c = (gtid / DINNER) % NCHUNK;
    int b = gtid / (DINNER * NCHUNK);
    float dtw[DTRANK];
    #pragma unroll
    for (int j = 0; j < DTRANK; j += 4)
        *(float4*)(dtw + j) = *(const float4*)(dt_w + (size_t)d * DTRANK + j);
    float dtbd = dt_b[d];
    float Av[DSTATE], P[DSTATE], S[DSTATE];
    #pragma unroll
    for (int s = 0; s < DSTATE; ++s) {
        Av[s] = -__expf(A_log[d * DSTATE + s]);
        P[s] = 1.f; S[s] = 0.f;
    }
    int t0 = c * CLEN;
    int rowb = b * LSEQ;
    for (int i = 0; i < CLEN; ++i) {
        int row = rowb + t0 + i;
        const float* xrow = xdbl + (size_t)row * XDSTR;
        float dl = compute_delta(xrow, dtw, dtbd);
        Dbuf[(size_t)row * DINNER + d] = dl;
        float u = __bfloat162float(u16[(size_t)row * DINNER + d]);
        float bt = dl * u;
        const float4* Bp = (const float4*)(xrow + DTRANK);
        float4 B0 = Bp[0], B1 = Bp[1], B2 = Bp[2], B3 = Bp[3];
        float Bv[DSTATE] = {B0.x,B0.y,B0.z,B0.w, B1.x,B1.y,B1.z,B1.w,
                            B2.x,B2.y,B2.z,B2.w, B3.x,B3.y,B3.z,B3.w};
        #pragma unroll
        for (int s = 0; s < DSTATE; ++s) {
            float a = __expf(dl * Av[s]);
            P[s] *= a;
            S[s] = a * S[s] + bt * Bv[s];
        }
    }
    size_t base = ((size_t)(b * NCHUNK + c) * DSTATE) * DINNER + d;
    #pragma unroll
    for (int s = 0; s < DSTATE; ++s) {
        Psum[base + (size_t)s * DINNER] = P[s];
        Ssum[base + (size_t)s * DINNER] = S[s];
    }
    // zero next layer's xdbl buffer (its last reader finished 2+ kernels ago)
    for (int z = gtid; z < BSZ * LSEQ * XDSTR; z += BSZ * NCHUNK * DINNER)
        xd_next[z] = 0.f;
}

// in-place exclusive prefix: Psum[idx] := h_before (chunk-incoming state)
__global__ __launch_bounds__(256) void scan_phaseB(
    float* __restrict__ Psum, const float* __restrict__ Ssum) {
    int gtid = blockIdx.x * 256 + threadIdx.x;
    int d = gtid % DINNER;
    int s = (gtid / DINNER) % DSTATE;
    int b = gtid / (DINNER * DSTATE);
    float h = 0.f;
    for (int c = 0; c < NCHUNK; ++c) {
        size_t idx = ((size_t)(b * NCHUNK + c) * DSTATE + s) * DINNER + d;
        float p = Psum[idx];
        Psum[idx] = h;
        h = p * h + Ssum[idx];
    }
}

// reads u from uy16, overwrites it with y; h0 from Psum (in-place), dl from Dbuf
__global__ __launch_bounds__(256) void scan_phaseC(
    bf16* __restrict__ uy16, const bf16* __restrict__ xz16,
    const float* __restrict__ xdbl,
    const float* __restrict__ A_log, const float* __restrict__ D_skip,
    const float* __restrict__ H0, const float* __restrict__ Dbuf) {
    int gtid = blockIdx.x * 256 + threadIdx.x;
    int d = gtid % DINNER;
    int c = (gtid / DINNER) % NCHUNK;
    int b = gtid / (DINNER * NCHUNK);
    float Av[DSTATE], h[DSTATE];
    size_t base = ((size_t)(b * NCHUNK + c) * DSTATE) * DINNER + d;
    #pragma unroll
    for (int s = 0; s < DSTATE; ++s) {
        Av[s] = -__expf(A_log[d * DSTATE + s]);
        h[s] = H0[base + (size_t)s * DINNER];
    }
    float Dsk = D_skip[d];
    int t0 = c * CLEN;
    int rowb = b * LSEQ;
    for (int i = 0; i < CLEN; ++i) {
        int row = rowb + t0 + i;
        const float* xrow = xdbl + (size_t)row * XDSTR;
        float dl = Dbuf[(size_t)row * DINNER + d];
        float u = __bfloat162float(uy16[(size_t)row * DINNER + d]);
        float bt = dl * u;
        const float4* Bp = (const float4*)(xrow + DTRANK);
        float4 B0 = Bp[0], B1 = Bp[1], B2 = Bp[2], B3 = Bp[3];
        const float4* Cp = (const float4*)(xrow + DTRANK + DSTATE);
        float4 C0 = Cp[0], C1 = Cp[1], C2 = Cp[2], C3 = Cp[3];
        float Bv[DSTATE] = {B0.x,B0.y,B0.z,B0.w, B1.x,B1.y,B1.z,B1.w,
                            B2.x,B2.y,B2.z,B2.w, B3.x,B3.y,B3.z,B3.w};
        float Cv[DSTATE] = {C0.x,C0.y,C0.z,C0.w, C1.x,C1.y,C1.z,C1.w,
                            C2.x,C2.y,C2.z,C2.w, C3.x,C3.y,C3.z,C3.w};
        float acc = 0.f;
        #pragma unroll
        for (int s = 0; s < DSTATE; ++s) {
            float a = __expf(dl * Av[s]);
            h[s] = a * h[s] + bt * Bv[s];
            acc += h[s] * Cv[s];
        }
        float zv = __bfloat162float(xz16[(size_t)row * XZLD + DINNER + d]);
        float sz = zv / (1.f + __expf(-zv));
        uy16[(size_t)row * DINNER + d] = __float2bfloat16((acc + u * Dsk) * sz);
    }
}

// ---------------- final: last-token rmsnorm over res + P0..P3 ----------------
__global__ __launch_bounds__(256) void final_acc_kernel(
    const float* __restrict__ res, const float* __restrict__ p0, const float* __restrict__ p1,
    const float* __restrict__ p2, const float* __restrict__ p3,
    const int* __restrict__ mask, const float* __restrict__ w, float* __restrict__ out) {
    __shared__ float sbuf[8];
    int b = blockIdx.x;
    float cnt = 0.f;
    for (int i = threadIdx.x; i < LSEQ; i += 256) cnt += (float)mask[b * LSEQ + i];
    cnt = block_reduce_sum(cnt, sbuf);
    int last = (int)cnt - 1;
    size_t base = ((size_t)b * LSEQ + last) * DMODEL;
    float ss = 0.f;
    for (int i = threadIdx.x; i < DMODEL; i += 256) {
        float v = res[base + i] + ((p0[base + i] + p1[base + i]) + (p2[base + i] + p3[base + i]));
        ss += v * v;
    }
    ss = block_reduce_sum(ss, sbuf);
    float scale = rsqrtf(ss / (float)DMODEL + 1e-5f);
    for (int i = threadIdx.x; i < DMODEL; i += 256) {
        float v = res[base + i] + ((p0[base + i] + p1[base + i]) + (p2[base + i] + p3[base + i]));
        out[b * DMODEL + i] = v * scale * w[i];
    }
}

extern "C" void kernel_launch(void* const* d_in, const int* in_sizes, int n_in,
                              void* d_out, int out_size, void* d_ws, size_t ws_size,
                              hipStream_t stream) {
    const int*   seq      = (const int*)d_in[0];
    const int*   mask     = (const int*)d_in[1];
    const float* emb      = (const float*)d_in[2];
    const float* norm_w   = (const float*)d_in[3];
    const float* in_w     = (const float*)d_in[4];
    const float* conv_w   = (const float*)d_in[5];
    const float* conv_b   = (const float*)d_in[6];
    const float* xp_w     = (const float*)d_in[7];
    const float* dt_w     = (const float*)d_in[8];
    const float* dt_b     = (const float*)d_in[9];
    const float* A_log    = (const float*)d_in[10];
    const float* D_skip   = (const float*)d_in[11];
    const float* out_w    = (const float*)d_in[12];
    const float* normf_w  = (const float*)d_in[13];
    float* out = (float*)d_out;

    char* ws = (char*)d_ws;
    float* residual = (float*)(ws);                      //  6,291,456
    bf16*  hn16     = (bf16*)(ws + 6291456);             //  3,145,728
    bf16*  xz16     = (bf16*)(ws + 9437184);             // 12,582,912
    float* xdbl     = (float*)(ws + 22020096);           //  2,097,152 (2 buffers)
    bf16*  uy16     = (bf16*)(ws + 24117248);            //  6,291,456 (u, then y in-place)
    float* Psum     = (float*)(ws + 30408704);           // 12,582,912 (P, then h0, then P0/P1)
    float* Ssum     = (float*)(ws + 42991616);           // 12,582,912 (S, then P2/P3)
    float* Dbuf     = (float*)(ws + 55574528);           // 12,582,912 (delta; ex-Hin)
    bf16*  in16     = (bf16*)(ws + 68157440);            // 18,874,368
    bf16*  out16    = (bf16*)(ws + 87031808);            //  9,437,184
    bf16*  xp16     = (bf16*)(ws + 96468992);            //  1,572,864
                                                         // total 98,041,856 bytes
    // out_proj partials: 4 x 6,291,456 B carved from Psum/Ssum (dead after scanC)
    float* P0 = Psum;
    float* P1 = Psum + (size_t)BSZ * LSEQ * DMODEL;      // 1,572,864 floats
    float* P2 = Ssum;
    float* P3 = Ssum + (size_t)BSZ * LSEQ * DMODEL;

    init_kernel<<<66560, 256, 0, stream>>>(seq, emb, in_w, out_w, xp_w,
                                           residual, in16, out16, xp16, xdbl);

    for (int i = 0; i < NLAYER; ++i) {
        float* xd_cur = xdbl + (size_t)(i & 1) * (BSZ * LSEQ * XDSTR);
        float* xd_nxt = xdbl + (size_t)((i + 1) & 1) * (BSZ * LSEQ * XDSTR);
        const float* cw = conv_w + (size_t)i * DINNER * DCONV;
        const float* cb = conv_b + (size_t)i * DINNER;
        const float* dw = dt_w + (size_t)i * DINNER * DTRANK;
        const float* db = dt_b + (size_t)i * DINNER;
        const float* al = A_log + (size_t)i * DINNER * DSTATE;

        if (i == 0)
            rmsnorm_kernel<<<BSZ * LSEQ, 256, 0, stream>>>(
                residual, norm_w, hn16);
        else
            rmsnorm_acc_kernel<<<BSZ * LSEQ, 256, 0, stream>>>(
                residual, P0, P1, P2, P3, norm_w + (size_t)i * DMODEL, hn16);
        // in_proj: xz16(2048x3072) = hn16 @ in16[i]^T  (grid 768, 3 blocks/CU)
        gemm_128x64_g<<<dim3(16, 48), 256, 0, stream>>>(
            hn16, DMODEL, in16 + (size_t)i * 3072 * DMODEL, DMODEL, xz16, XZLD, DMODEL);
        // u = silu(conv(x)+cb): throughput kernel, writes uy16
        usilu_kernel<<<(BSZ * LSEQ * UCHUNKS) / 256, 256, 0, stream>>>(xz16, cw, cb, uy16);
        // x_proj: xdbl(2048x128) f32 = u @ xp16[i]^T, split-K=8 atomic (grid 512)
        gemm_64_atomic_g<<<dim3(32, 2, 8), 256, 0, stream>>>(
            uy16, DINNER, xp16 + (size_t)i * 128 * DINNER, DINNER, xd_cur, XDSTR, DINNER);
        scan_phaseA<<<768, 256, 0, stream>>>(
            uy16, xd_cur, dw, db, al, Psum, Ssum, Dbuf, xd_nxt);
        scan_phaseB<<<192, 256, 0, stream>>>(Psum, Ssum);
        scan_phaseC<<<768, 256, 0, stream>>>(
            uy16, xz16, xd_cur, al, D_skip + (size_t)i * DINNER, Psum, Dbuf);
        // out_proj partials: P0..P3(2048x768) = y @ out16[i]^T, 128x64 tile, split-K=4
        gemm_128x64_part_g<<<dim3(16, 12, 4), 256, 0, stream>>>(
            uy16, DINNER, out16 + (size_t)i * DMODEL * DINNER, DINNER,
            P0, P1, P2, P3, DMODEL, DINNER);
    }

    final_acc_kernel<<<BSZ, 256, 0, stream>>>(residual, P0, P1, P2, P3, mask, normf_w, out);
}